// Round 5
// baseline (503.915 us; speedup 1.0000x reference)
//
#include <hip/hip_runtime.h>
#include <hip/hip_fp16.h>
#include <stdint.h>

#define FP8_MAX_V 448.0f
#define BM 256
#define BN 256
#define BKB 64   // K-bytes per K-tile (fp8 => 64 elements); LDS row = 64 B
#define NSLOT 4  // LDS ring slots => 2-tile prefetch lead
#define SLOTB (BM * BKB)  // 16 KB per operand per slot

typedef float floatx4 __attribute__((ext_vector_type(4)));

// asm wait/barrier with full compiler fencing (rule #18).
#define WAITVM(n)                                              \
  do {                                                         \
    asm volatile("s_waitcnt vmcnt(" #n ")" ::: "memory");      \
    __builtin_amdgcn_sched_barrier(0);                         \
  } while (0)
#define WAITLGKM0()                                            \
  do {                                                         \
    asm volatile("s_waitcnt lgkmcnt(0)" ::: "memory");         \
    __builtin_amdgcn_sched_barrier(0);                         \
  } while (0)
#define BARRIER()                                              \
  do {                                                         \
    __builtin_amdgcn_sched_barrier(0);                         \
    __builtin_amdgcn_s_barrier();                              \
    __builtin_amdgcn_sched_barrier(0);                         \
  } while (0)

// Deterministic bf16 round-to-nearest-even of an fp32 value, returned widened to fp32.
__device__ __forceinline__ float bf16_rne(float v) {
  uint32_t u = __float_as_uint(v);
  u = (u + 0x7fffu + ((u >> 16) & 1u)) & 0xffff0000u;
  return __uint_as_float(u);
}

// Pack 4 fp32 (already clipped to +-448) into 4 OCP e4m3fn bytes via HW RNE cvt.
__device__ __forceinline__ uint32_t pack4_fp8(float a, float b, float c, float d) {
  int p = 0;
  p = __builtin_amdgcn_cvt_pk_fp8_f32(a, b, p, false);  // bytes 0..1
  p = __builtin_amdgcn_cvt_pk_fp8_f32(c, d, p, true);   // bytes 2..3
  return (uint32_t)p;
}

__device__ __forceinline__ void gload_lds16(const uint8_t* g, uint8_t* l) {
  __builtin_amdgcn_global_load_lds(
      (const __attribute__((address_space(1))) uint32_t*)g,
      (__attribute__((address_space(3))) uint32_t*)l,
      16, 0, 0);
}

// Per-row quantization: amax over K -> scale -> fp8. FP16RT: fp16 round-trip the
// scale (weight path, matches reference's scale.astype(fp16).astype(fp32)).
template <bool FP16RT>
__global__ __launch_bounds__(256) void quant_rows_kernel(
    const float* __restrict__ in, uint8_t* __restrict__ out8,
    float* __restrict__ scales, int K) {
  const int row = blockIdx.x;
  const int tid = threadIdx.x;
  const float* rp = in + (size_t)row * K;

  float4 v[4];
  float amax = 0.f;
#pragma unroll
  for (int i = 0; i < 4; ++i) {
    v[i] = ((const float4*)rp)[i * 256 + tid];
    amax = fmaxf(amax, fmaxf(fmaxf(fabsf(v[i].x), fabsf(v[i].y)),
                             fmaxf(fabsf(v[i].z), fabsf(v[i].w))));
  }
#pragma unroll
  for (int off = 32; off; off >>= 1) amax = fmaxf(amax, __shfl_xor(amax, off));
  __shared__ float red[4];
  if ((tid & 63) == 0) red[tid >> 6] = amax;
  __syncthreads();
  amax = fmaxf(fmaxf(red[0], red[1]), fmaxf(red[2], red[3]));

  float scale = fmaxf(amax / FP8_MAX_V, 1e-6f);
  if (FP16RT) scale = __half2float(__float2half(scale));  // RNE fp16 round-trip
  if (tid == 0) scales[row] = scale;

  uint32_t* op = (uint32_t*)(out8 + (size_t)row * K);
#pragma unroll
  for (int i = 0; i < 4; ++i) {
    float qa = fminf(fmaxf(v[i].x / scale, -FP8_MAX_V), FP8_MAX_V);
    float qb = fminf(fmaxf(v[i].y / scale, -FP8_MAX_V), FP8_MAX_V);
    float qc = fminf(fmaxf(v[i].z / scale, -FP8_MAX_V), FP8_MAX_V);
    float qd = fminf(fmaxf(v[i].w / scale, -FP8_MAX_V), FP8_MAX_V);
    op[i * 256 + tid] = pack4_fp8(qa, qb, qc, qd);
  }
}

// C[t,o] = sum_k A8[t,k]*B8[o,k] (both K-major), scaled + bias + bf16 round.
// m201 8-phase template, fp8 port: 256x256 tile, 512 thr = 8 waves (2M x 4N),
// per-wave 128x64 = 8x4 frags of 16x16x32 fp8 MFMA. K-tile = 64 fp8 (64B rows),
// 4-slot LDS ring (128 KB) = 2-tile lead. Per K-tile, 4 C-quadrant phases:
// {12 ds_read_b64 || 1 gload_lds of tile t+2 -> barrier -> lgkmcnt(0) ->
//  setprio(1) 16 MFMA setprio(0) -> barrier}. Counted vmcnt(4) once per tile
// (never 0 until tail). K-accumulation order identical to prior rounds.
//
// Swizzle (T2, rule #21): 16B chunk within each 64B row XOR'd with (row&3);
// linear LDS dest (gload_lds) + inverse-swizzled global source + swizzled
// read. b64 reads: 16 distinct even banks x 4-way = the 512B/instr BW floor.
__global__ __launch_bounds__(512, 2) void gemm_fp8_kernel(
    const uint8_t* __restrict__ A8, const uint8_t* __restrict__ B8,
    const float* __restrict__ asc, const float* __restrict__ wsc,
    const float* __restrict__ bias, float* __restrict__ out,
    int M, int N, int K) {
  __shared__ __align__(16) uint8_t As[NSLOT * SLOTB];  // 64 KB
  __shared__ __align__(16) uint8_t Bs[NSLOT * SLOTB];  // 64 KB

  const int tid = threadIdx.x;
  const int lane = tid & 63;
  const int wid = tid >> 6;
  const int wr = wid >> 2;  // 0..1 (M dimension, 128 rows each)
  const int wc = wid & 3;   // 0..3 (N dimension, 64 cols each)

  const int ntn = N / BN;
  const int bm = blockIdx.x / ntn;
  const int bn = blockIdx.x % ntn;

  floatx4 acc[8][4] = {};

  // Staging: thread tid -> LDS linear offset tid*16 (row=tid>>2, chunk=tid&3);
  // global source chunk = (tid&3) ^ (row&3). Second load at row+128 (row&3
  // preserved), LDS +8192.
  const int srow = tid >> 2;                   // 0..127
  const int sc_log = (tid & 3) ^ (srow & 3);   // pre-swizzled source chunk
  const uint8_t* gA = A8 + (size_t)(bm * BM + srow) * K + sc_log * 16;
  const uint8_t* gB = B8 + (size_t)(bn * BN + srow) * K + sc_log * 16;
  const size_t rstep = (size_t)128 * K;

  const int fr = lane & 15;       // fragment row/col within 16
  const int hi = lane >> 4;       // 0..3, K sub-chunk selector
  // read offset within a 64B row for K-step ks: chunk=(ks*2+(hi>>1))^(fr&3)
  const int kof0 = (((0 << 1) + (hi >> 1)) ^ (fr & 3)) * 16 + (hi & 1) * 8;
  const int kof1 = (((1 << 1) + (hi >> 1)) ^ (fr & 3)) * 16 + (hi & 1) * 8;
  const int arowoff = (wr * 128 + fr) * 64;  // + m*1024
  const int bcoloff = (wc * 64 + fr) * 64;   // + n*1024

  // Stage the full K-tile at k0 into slot s (prologue only): A0,A1,B0,B1.
  auto stage_tile = [&](int s, int k0) {
    uint8_t* lA = As + s * SLOTB + tid * 16;
    uint8_t* lB = Bs + s * SLOTB + tid * 16;
    gload_lds16(gA + k0, lA);
    gload_lds16(gA + rstep + k0, lA + 8192);
    gload_lds16(gB + k0, lB);
    gload_lds16(gB + rstep + k0, lB + 8192);
  };

  const int NT = K / BKB;  // 64
  stage_tile(0, 0);
  stage_tile(1, BKB);

  for (int t = 0; t < NT; ++t) {
    const int s = t & (NSLOT - 1);
    // Wait for tile t's 4 loads; tile t+1's 4 stay in flight.
    if (t + 1 < NT) { WAITVM(4); } else { WAITVM(0); }
    BARRIER();

    const uint8_t* Ab = As + s * SLOTB;
    const uint8_t* Bb = Bs + s * SLOTB;
    const int s2 = (t + 2) & (NSLOT - 1);
    const bool pf = (t + 2) < NT;
    const int k2 = (t + 2) * BKB;
    uint8_t* lA2 = As + s2 * SLOTB + tid * 16;
    uint8_t* lB2 = Bs + s2 * SLOTB + tid * 16;

#pragma unroll
    for (int q = 0; q < 4; ++q) {
      const int mh = q >> 1, nh = q & 1;
      int64_t a[4][2], b[2][2];
#pragma unroll
      for (int m = 0; m < 4; ++m) {
        const int ro = arowoff + (mh * 4 + m) * 1024;
        a[m][0] = *(const int64_t*)(Ab + ro + kof0);
        a[m][1] = *(const int64_t*)(Ab + ro + kof1);
      }
#pragma unroll
      for (int n = 0; n < 2; ++n) {
        const int ro = bcoloff + (nh * 2 + n) * 1024;
        b[n][0] = *(const int64_t*)(Bb + ro + kof0);
        b[n][1] = *(const int64_t*)(Bb + ro + kof1);
      }
      if (pf) {  // one stage-load of tile t+2 per phase (A0,A1,B0,B1)
        if (q == 0) gload_lds16(gA + k2, lA2);
        else if (q == 1) gload_lds16(gA + rstep + k2, lA2 + 8192);
        else if (q == 2) gload_lds16(gB + k2, lB2);
        else gload_lds16(gB + rstep + k2, lB2 + 8192);
      }
      BARRIER();      // ds_reads + stage issued; waves converge
      WAITLGKM0();    // all 12 ds_reads complete (rule #18 fence follows)
      __builtin_amdgcn_s_setprio(1);
#pragma unroll
      for (int ks = 0; ks < 2; ++ks)
#pragma unroll
        for (int m = 0; m < 4; ++m)
#pragma unroll
          for (int n = 0; n < 2; ++n)
            acc[mh * 4 + m][nh * 2 + n] = __builtin_amdgcn_mfma_f32_16x16x32_fp8_fp8(
                a[m][ks], b[n][ks], acc[mh * 4 + m][nh * 2 + n], 0, 0, 0);
      __builtin_amdgcn_s_setprio(0);
      if (q < 3) BARRIER();  // tile-end barrier folded into loop-head WAITVM+BARRIER
    }
  }

  // Epilogue: C/D 16x16 layout col=lane&15, row=(lane>>4)*4+r (dtype-independent).
  const int rbase = bm * BM + wr * 128;
  const int cbase = bn * BN + wc * 64;
#pragma unroll
  for (int n = 0; n < 4; ++n) {
    const int col = cbase + n * 16 + fr;
    const float wv = wsc[col];
    const float bb = bf16_rne(bias[col]);  // bias.astype(bf16).astype(f32)
#pragma unroll
    for (int m = 0; m < 8; ++m) {
      const int r0 = rbase + m * 16 + hi * 4;
#pragma unroll
      for (int r = 0; r < 4; ++r) {
        const int row = r0 + r;
        // reference order: (acc * act_scale) * w_scale + bias_bf16, then bf16 RNE
        float v = (acc[m][n][r] * asc[row]) * wv + bb;
        out[(size_t)row * N + col] = bf16_rne(v);
      }
    }
  }
}

extern "C" void kernel_launch(void* const* d_in, const int* in_sizes, int n_in,
                              void* d_out, int out_size, void* d_ws, size_t ws_size,
                              hipStream_t stream) {
  const float* x = (const float*)d_in[0];     // [B,S,K] f32
  const float* w = (const float*)d_in[1];     // [N,K] f32
  const float* bias = (const float*)d_in[2];  // [N] f32
  float* out = (float*)d_out;                 // [M,N] f32 (bf16-rounded values)

  const int N = in_sizes[2];             // 4096 (D_OUT)
  const int K = in_sizes[1] / N;         // 4096 (D_IN)
  const int M = in_sizes[0] / K;         // 8192 tokens

  uint8_t* x8 = (uint8_t*)d_ws;                    // M*K bytes
  uint8_t* w8 = x8 + (size_t)M * K;                // N*K bytes
  float* asc = (float*)(w8 + (size_t)N * K);       // M floats
  float* wsc = asc + M;                            // N floats
  (void)ws_size; (void)n_in; (void)out_size;

  quant_rows_kernel<false><<<M, 256, 0, stream>>>(x, x8, asc, K);
  quant_rows_kernel<true><<<N, 256, 0, stream>>>(w, w8, wsc, K);
  gemm_fp8_kernel<<<(M / BM) * (N / BN), 512, 0, stream>>>(x8, w8, asc, wsc, bias, out, M, N, K);
}

// Round 6
// 267.957 us; speedup vs baseline: 1.8806x; 1.8806x over previous
//
#include <hip/hip_runtime.h>
#include <hip/hip_fp16.h>
#include <stdint.h>

#define FP8_MAX_V 448.0f
#define BM 128
#define BN 128
#define BKB 128  // K-bytes per tile step (fp8 => 128 elements); LDS row = 128 B

typedef float floatx4 __attribute__((ext_vector_type(4)));

// asm wait/barrier with full compiler fencing (rule #18).
#define WAITVM(n)                                              \
  do {                                                         \
    asm volatile("s_waitcnt vmcnt(" #n ")" ::: "memory");      \
    __builtin_amdgcn_sched_barrier(0);                         \
  } while (0)
#define BARRIER()                                              \
  do {                                                         \
    __builtin_amdgcn_sched_barrier(0);                         \
    __builtin_amdgcn_s_barrier();                              \
    __builtin_amdgcn_sched_barrier(0);                         \
  } while (0)

// Deterministic bf16 round-to-nearest-even of an fp32 value, returned widened to fp32.
__device__ __forceinline__ float bf16_rne(float v) {
  uint32_t u = __float_as_uint(v);
  u = (u + 0x7fffu + ((u >> 16) & 1u)) & 0xffff0000u;
  return __uint_as_float(u);
}

// Pack 4 fp32 (already clipped to +-448) into 4 OCP e4m3fn bytes via HW RNE cvt.
__device__ __forceinline__ uint32_t pack4_fp8(float a, float b, float c, float d) {
  int p = 0;
  p = __builtin_amdgcn_cvt_pk_fp8_f32(a, b, p, false);  // bytes 0..1
  p = __builtin_amdgcn_cvt_pk_fp8_f32(c, d, p, true);   // bytes 2..3
  return (uint32_t)p;
}

__device__ __forceinline__ void gload_lds16(const uint8_t* g, uint8_t* l) {
  __builtin_amdgcn_global_load_lds(
      (const __attribute__((address_space(1))) uint32_t*)g,
      (__attribute__((address_space(3))) uint32_t*)l,
      16, 0, 0);
}

// Per-row quantization: amax over K -> scale -> fp8. FP16RT: fp16 round-trip the
// scale (weight path, matches reference's scale.astype(fp16).astype(fp32)).
template <bool FP16RT>
__global__ __launch_bounds__(256) void quant_rows_kernel(
    const float* __restrict__ in, uint8_t* __restrict__ out8,
    float* __restrict__ scales, int K) {
  const int row = blockIdx.x;
  const int tid = threadIdx.x;
  const float* rp = in + (size_t)row * K;

  // K = 4096: 16 floats/thread as 4x float4, coalesced (stride-256 float4s).
  float4 v[4];
  float amax = 0.f;
#pragma unroll
  for (int i = 0; i < 4; ++i) {
    v[i] = ((const float4*)rp)[i * 256 + tid];
    amax = fmaxf(amax, fmaxf(fmaxf(fabsf(v[i].x), fabsf(v[i].y)),
                             fmaxf(fabsf(v[i].z), fabsf(v[i].w))));
  }
#pragma unroll
  for (int off = 32; off; off >>= 1) amax = fmaxf(amax, __shfl_xor(amax, off));
  __shared__ float red[4];
  if ((tid & 63) == 0) red[tid >> 6] = amax;
  __syncthreads();
  amax = fmaxf(fmaxf(red[0], red[1]), fmaxf(red[2], red[3]));

  float scale = fmaxf(amax / FP8_MAX_V, 1e-6f);
  if (FP16RT) scale = __half2float(__float2half(scale));  // RNE, matches jnp fp16 round-trip
  if (tid == 0) scales[row] = scale;

  uint32_t* op = (uint32_t*)(out8 + (size_t)row * K);
#pragma unroll
  for (int i = 0; i < 4; ++i) {
    // true fp32 division (correctly rounded) to match numpy's x / scale
    float qa = fminf(fmaxf(v[i].x / scale, -FP8_MAX_V), FP8_MAX_V);
    float qb = fminf(fmaxf(v[i].y / scale, -FP8_MAX_V), FP8_MAX_V);
    float qc = fminf(fmaxf(v[i].z / scale, -FP8_MAX_V), FP8_MAX_V);
    float qd = fminf(fmaxf(v[i].w / scale, -FP8_MAX_V), FP8_MAX_V);
    op[i * 256 + tid] = pack4_fp8(qa, qb, qc, qd);
  }
}

// C[t,o] = sum_k A8[t,k]*B8[o,k]  (both K-major), scaled + bias + bf16 round.
// Round-3 base (proven 51% MfmaUtil): 128x128 tile, BKB=128, 4 waves 2x2,
// per-wave 64x64 = 4x4 frags of 16x16x32 fp8 MFMA, compiler-scheduled ks-loop,
// 64 KB LDS -> 2 blocks/CU.
//
// T4 upgrade (this round): 2-tile prefetch lead with COUNTED vmcnt. Prologue
// stages tiles 0,1; loop head waits vmcnt(8) (drains exactly tile t's 8 loads,
// keeps tile t+1's 8 in flight) + barrier; compute; barrier; restage the freed
// slot with tile t+2. Loads get ~2 compute spans of cover; no full drain.
// Race-free: slot rewritten only after the barrier ending its reads; slot read
// only after every wave's own WAITVM + barrier.
//
// LDS swizzle (T2, rule #21 both-sides): 16B chunk c16 within each 128B row
// XOR'd with (row&7); linear LDS dest (gload_lds) + pre-swizzled global
// source + swizzled read. Measured at the 4 cyc/read b64 floor.
__global__ __launch_bounds__(256) void gemm_fp8_kernel(
    const uint8_t* __restrict__ A8, const uint8_t* __restrict__ B8,
    const float* __restrict__ asc, const float* __restrict__ wsc,
    const float* __restrict__ bias, float* __restrict__ out,
    int M, int N, int K) {
  __shared__ __align__(16) uint8_t As[2][BM * BKB];  // 2 x 16 KB
  __shared__ __align__(16) uint8_t Bs[2][BN * BKB];  // 2 x 16 KB

  const int tid = threadIdx.x;
  const int lane = tid & 63;
  const int wid = tid >> 6;
  const int wr = wid >> 1;  // 0..1
  const int wc = wid & 1;   // 0..1

  const int ntn = N / BN;
  const int bm = blockIdx.x / ntn;
  const int bn = blockIdx.x % ntn;

  floatx4 acc[4][4] = {};

  // Staging: thread tid -> LDS linear offset tid*16 (row=tid>>3, c16_phys=tid&7),
  // global source chunk = c16_phys ^ (row&7). Row stride 32 between the 4 calls
  // preserves (row&7), so one source offset serves all calls.
  const int srow = tid >> 3;                      // 0..31
  const int sc_log = (tid & 7) ^ (srow & 7);      // pre-swizzled source chunk
  const uint8_t* ga0 = A8 + (size_t)(bm * BM + srow) * K + sc_log * 16;
  const uint8_t* gb0 = B8 + (size_t)(bn * BN + srow) * K + sc_log * 16;
  const size_t rstep = (size_t)32 * K;

  const int fr = lane & 15;        // fragment row/col within 16
  const int hi = lane >> 4;        // K sub-chunk selector
  const int bofs = (hi & 1) * 8;   // byte offset within 16B chunk
  const int hb = hi >> 1;
  const int fsw = fr & 7;          // read-side swizzle key

  // Stage one K-tile (8 x 16B per thread) into buffer `buf` at K offset k0.
  auto stage = [&](int buf, int k0) {
    uint8_t* lA = As[buf] + tid * 16;
    uint8_t* lB = Bs[buf] + tid * 16;
#pragma unroll
    for (int i = 0; i < 4; ++i) gload_lds16(ga0 + i * rstep + k0, lA + i * 4096);
#pragma unroll
    for (int i = 0; i < 4; ++i) gload_lds16(gb0 + i * rstep + k0, lB + i * 4096);
  };

  auto compute = [&](int buf) {
    const uint8_t* Ab = As[buf];
    const uint8_t* Bb = Bs[buf];
#pragma unroll
    for (int ks = 0; ks < 4; ++ks) {
      const int koff = ((ks * 2 + hb) ^ fsw) * 16 + bofs;  // swizzled read offset
      int64_t a[4], b[4];
#pragma unroll
      for (int m = 0; m < 4; ++m)
        a[m] = *(const int64_t*)(Ab + (size_t)(wr * 64 + m * 16 + fr) * BKB + koff);
#pragma unroll
      for (int n = 0; n < 4; ++n)
        b[n] = *(const int64_t*)(Bb + (size_t)(wc * 64 + n * 16 + fr) * BKB + koff);
#pragma unroll
      for (int m = 0; m < 4; ++m)
#pragma unroll
        for (int n = 0; n < 4; ++n)
          acc[m][n] = __builtin_amdgcn_mfma_f32_16x16x32_fp8_fp8(a[m], b[n], acc[m][n], 0, 0, 0);
    }
  };

  const int NT = K / BKB;  // 32
  stage(0, 0);
  stage(1, BKB);

  for (int t = 0; t < NT; ++t) {
    const int cur = t & 1;
    // Drain exactly tile t's 8 loads; tile t+1's 8 stay in flight.
    if (t + 1 < NT) WAITVM(8); else WAITVM(0);
    BARRIER();   // every wave has waited for its tile-t loads -> slot cur ready
    compute(cur);
    BARRIER();   // all waves done reading slot cur -> safe to rewrite
    if (t + 2 < NT) stage(cur, (t + 2) * BKB);
  }

  // Epilogue: C/D 16x16 layout col=lane&15, row=(lane>>4)*4+r (dtype-independent).
  const int rbase = bm * BM + wr * 64;
  const int cbase = bn * BN + wc * 64;
#pragma unroll
  for (int n = 0; n < 4; ++n) {
    const int col = cbase + n * 16 + fr;
    const float wv = wsc[col];
    const float bb = bf16_rne(bias[col]);  // bias.astype(bf16).astype(f32)
#pragma unroll
    for (int m = 0; m < 4; ++m) {
      const int r0 = rbase + m * 16 + hi * 4;
#pragma unroll
      for (int r = 0; r < 4; ++r) {
        const int row = r0 + r;
        // reference order: (acc * act_scale) * w_scale + bias_bf16, then bf16 RNE
        float v = (acc[m][n][r] * asc[row]) * wv + bb;
        out[(size_t)row * N + col] = bf16_rne(v);
      }
    }
  }
}

extern "C" void kernel_launch(void* const* d_in, const int* in_sizes, int n_in,
                              void* d_out, int out_size, void* d_ws, size_t ws_size,
                              hipStream_t stream) {
  const float* x = (const float*)d_in[0];     // [B,S,K] f32
  const float* w = (const float*)d_in[1];     // [N,K] f32
  const float* bias = (const float*)d_in[2];  // [N] f32
  float* out = (float*)d_out;                 // [M,N] f32 (bf16-rounded values)

  const int N = in_sizes[2];             // 4096 (D_OUT)
  const int K = in_sizes[1] / N;         // 4096 (D_IN)
  const int M = in_sizes[0] / K;         // 8192 tokens

  uint8_t* x8 = (uint8_t*)d_ws;                    // M*K bytes
  uint8_t* w8 = x8 + (size_t)M * K;                // N*K bytes
  float* asc = (float*)(w8 + (size_t)N * K);       // M floats
  float* wsc = asc + M;                            // N floats
  (void)ws_size; (void)n_in; (void)out_size;

  quant_rows_kernel<false><<<M, 256, 0, stream>>>(x, x8, asc, K);
  quant_rows_kernel<true><<<N, 256, 0, stream>>>(w, w8, wsc, K);
  gemm_fp8_kernel<<<(M / BM) * (N / BN), 256, 0, stream>>>(x8, w8, asc, wsc, bias, out, M, N, K);
}

// Round 7
// 196.352 us; speedup vs baseline: 2.5664x; 1.3647x over previous
//
#include <hip/hip_runtime.h>
#include <hip/hip_fp16.h>
#include <stdint.h>

#define FP8_MAX_V 448.0f
#define BM 128
#define BN 128
#define BKB 128  // K-bytes per tile step (fp8 => 128 elements); LDS row = 128 B

typedef float floatx4 __attribute__((ext_vector_type(4)));
typedef int intx4 __attribute__((ext_vector_type(4)));
typedef int intx8 __attribute__((ext_vector_type(8)));

// asm wait/barrier with full compiler fencing (rule #18).
#define WAITVM(n)                                              \
  do {                                                         \
    asm volatile("s_waitcnt vmcnt(" #n ")" ::: "memory");      \
    __builtin_amdgcn_sched_barrier(0);                         \
  } while (0)
#define BARRIER()                                              \
  do {                                                         \
    __builtin_amdgcn_sched_barrier(0);                         \
    __builtin_amdgcn_s_barrier();                              \
    __builtin_amdgcn_sched_barrier(0);                         \
  } while (0)

// Deterministic bf16 round-to-nearest-even of an fp32 value, returned widened to fp32.
__device__ __forceinline__ float bf16_rne(float v) {
  uint32_t u = __float_as_uint(v);
  u = (u + 0x7fffu + ((u >> 16) & 1u)) & 0xffff0000u;
  return __uint_as_float(u);
}

// Pack 4 fp32 (already clipped to +-448) into 4 OCP e4m3fn bytes via HW RNE cvt.
__device__ __forceinline__ uint32_t pack4_fp8(float a, float b, float c, float d) {
  int p = 0;
  p = __builtin_amdgcn_cvt_pk_fp8_f32(a, b, p, false);  // bytes 0..1
  p = __builtin_amdgcn_cvt_pk_fp8_f32(c, d, p, true);   // bytes 2..3
  return (uint32_t)p;
}

__device__ __forceinline__ void gload_lds16(const uint8_t* g, uint8_t* l) {
  __builtin_amdgcn_global_load_lds(
      (const __attribute__((address_space(1))) uint32_t*)g,
      (__attribute__((address_space(3))) uint32_t*)l,
      16, 0, 0);
}

// Per-row quantization: amax over K -> scale -> fp8. FP16RT: fp16 round-trip the
// scale (weight path, matches reference's scale.astype(fp16).astype(fp32)).
template <bool FP16RT>
__global__ __launch_bounds__(256) void quant_rows_kernel(
    const float* __restrict__ in, uint8_t* __restrict__ out8,
    float* __restrict__ scales, int K) {
  const int row = blockIdx.x;
  const int tid = threadIdx.x;
  const float* rp = in + (size_t)row * K;

  // K = 4096: 16 floats/thread as 4x float4, coalesced (stride-256 float4s).
  float4 v[4];
  float amax = 0.f;
#pragma unroll
  for (int i = 0; i < 4; ++i) {
    v[i] = ((const float4*)rp)[i * 256 + tid];
    amax = fmaxf(amax, fmaxf(fmaxf(fabsf(v[i].x), fabsf(v[i].y)),
                             fmaxf(fabsf(v[i].z), fabsf(v[i].w))));
  }
#pragma unroll
  for (int off = 32; off; off >>= 1) amax = fmaxf(amax, __shfl_xor(amax, off));
  __shared__ float red[4];
  if ((tid & 63) == 0) red[tid >> 6] = amax;
  __syncthreads();
  amax = fmaxf(fmaxf(red[0], red[1]), fmaxf(red[2], red[3]));

  float scale = fmaxf(amax / FP8_MAX_V, 1e-6f);
  if (FP16RT) scale = __half2float(__float2half(scale));  // RNE, matches jnp fp16 round-trip
  if (tid == 0) scales[row] = scale;

  uint32_t* op = (uint32_t*)(out8 + (size_t)row * K);
#pragma unroll
  for (int i = 0; i < 4; ++i) {
    // true fp32 division (correctly rounded) to match numpy's x / scale
    float qa = fminf(fmaxf(v[i].x / scale, -FP8_MAX_V), FP8_MAX_V);
    float qb = fminf(fmaxf(v[i].y / scale, -FP8_MAX_V), FP8_MAX_V);
    float qc = fminf(fmaxf(v[i].z / scale, -FP8_MAX_V), FP8_MAX_V);
    float qd = fminf(fmaxf(v[i].w / scale, -FP8_MAX_V), FP8_MAX_V);
    op[i * 256 + tid] = pack4_fp8(qa, qb, qc, qd);
  }
}

// C[t,o] = sum_k A8[t,k]*B8[o,k]  (both K-major), scaled + bias + bf16 round.
// Round-6 structure (128x128 tile, BKB=128, 4 waves 2x2, 2-tile counted-vmcnt
// pipeline, 16B-chunk XOR swizzle) with the MFMA upgraded to the MX-scaled
// mfma_scale_f32_16x16x128_f8f6f4 with UNIT scales (e8m0 0x7F = 2^0): same
// fp8 e4m3 math at 2x the MFMA rate, 4x fewer MFMA instructions (m148 ladder
// step). Per lane a fragment is 32 CONTIGUOUS bytes = 2 x ds_read_b128 at
// independently-swizzled 16B chunks {2*hi, 2*hi+1} ^ (fr&7).
//
// Race-free: slot rewritten only after the barrier ending its reads; slot
// read only after every wave's own WAITVM + barrier.
__global__ __launch_bounds__(256) void gemm_fp8_kernel(
    const uint8_t* __restrict__ A8, const uint8_t* __restrict__ B8,
    const float* __restrict__ asc, const float* __restrict__ wsc,
    const float* __restrict__ bias, float* __restrict__ out,
    int M, int N, int K) {
  __shared__ __align__(16) uint8_t As[2][BM * BKB];  // 2 x 16 KB
  __shared__ __align__(16) uint8_t Bs[2][BN * BKB];  // 2 x 16 KB

  const int tid = threadIdx.x;
  const int lane = tid & 63;
  const int wid = tid >> 6;
  const int wr = wid >> 1;  // 0..1
  const int wc = wid & 1;   // 0..1

  const int ntn = N / BN;
  const int bm = blockIdx.x / ntn;
  const int bn = blockIdx.x % ntn;

  floatx4 acc[4][4] = {};

  // Staging: thread tid -> LDS linear offset tid*16 (row=tid>>3, c16_phys=tid&7),
  // global source chunk = c16_phys ^ (row&7). Row stride 32 between the 4 calls
  // preserves (row&7), so one source offset serves all calls.
  const int srow = tid >> 3;                      // 0..31
  const int sc_log = (tid & 7) ^ (srow & 7);      // pre-swizzled source chunk
  const uint8_t* ga0 = A8 + (size_t)(bm * BM + srow) * K + sc_log * 16;
  const uint8_t* gb0 = B8 + (size_t)(bn * BN + srow) * K + sc_log * 16;
  const size_t rstep = (size_t)32 * K;

  const int fr = lane & 15;        // fragment row/col within 16
  const int hi = lane >> 4;        // 0..3: K-block of 32 elems within the 128-tile
  const int fsw = fr & 7;          // read-side swizzle key
  // Lane's 32B fragment = chunks {2*hi, 2*hi+1}, each XOR-swizzled.
  const int cls = ((2 * hi) ^ fsw) * 16;      // low 16B chunk byte offset
  const int chs = ((2 * hi + 1) ^ fsw) * 16;  // high 16B chunk byte offset

  // Stage one K-tile (8 x 16B per thread) into buffer `buf` at K offset k0.
  auto stage = [&](int buf, int k0) {
    uint8_t* lA = As[buf] + tid * 16;
    uint8_t* lB = Bs[buf] + tid * 16;
#pragma unroll
    for (int i = 0; i < 4; ++i) gload_lds16(ga0 + i * rstep + k0, lA + i * 4096);
#pragma unroll
    for (int i = 0; i < 4; ++i) gload_lds16(gb0 + i * rstep + k0, lB + i * 4096);
  };

  auto compute = [&](int buf) {
    const uint8_t* Ab = As[buf];
    const uint8_t* Bb = Bs[buf];
    intx8 a[4], b[4];
#pragma unroll
    for (int m = 0; m < 4; ++m) {
      const uint8_t* p = Ab + (size_t)(wr * 64 + m * 16 + fr) * BKB;
      intx4 lo = *(const intx4*)(p + cls);
      intx4 hh = *(const intx4*)(p + chs);
      a[m] = (intx8){lo.x, lo.y, lo.z, lo.w, hh.x, hh.y, hh.z, hh.w};
    }
#pragma unroll
    for (int n = 0; n < 4; ++n) {
      const uint8_t* p = Bb + (size_t)(wc * 64 + n * 16 + fr) * BKB;
      intx4 lo = *(const intx4*)(p + cls);
      intx4 hh = *(const intx4*)(p + chs);
      b[n] = (intx8){lo.x, lo.y, lo.z, lo.w, hh.x, hh.y, hh.z, hh.w};
    }
#pragma unroll
    for (int m = 0; m < 4; ++m)
#pragma unroll
      for (int n = 0; n < 4; ++n)
        // cbsz=0 (A=fp8 e4m3), blgp=0 (B=fp8 e4m3), scales = e8m0 0x7F = 1.0
        acc[m][n] = __builtin_amdgcn_mfma_scale_f32_16x16x128_f8f6f4(
            a[m], b[n], acc[m][n], 0, 0, 0, 0x7F7F7F7F, 0, 0x7F7F7F7F);
  };

  const int NT = K / BKB;  // 32
  stage(0, 0);
  stage(1, BKB);

  for (int t = 0; t < NT; ++t) {
    const int cur = t & 1;
    // Drain exactly tile t's 8 loads; tile t+1's 8 stay in flight.
    if (t + 1 < NT) WAITVM(8); else WAITVM(0);
    BARRIER();   // every wave has waited for its tile-t loads -> slot cur ready
    compute(cur);
    BARRIER();   // all waves done reading slot cur -> safe to rewrite
    if (t + 2 < NT) stage(cur, (t + 2) * BKB);
  }

  // Epilogue: C/D 16x16 layout col=lane&15, row=(lane>>4)*4+r (dtype-independent;
  // f8f6f4-scaled C/D layout is shape-determined per m121-m128).
  const int rbase = bm * BM + wr * 64;
  const int cbase = bn * BN + wc * 64;
#pragma unroll
  for (int n = 0; n < 4; ++n) {
    const int col = cbase + n * 16 + fr;
    const float wv = wsc[col];
    const float bb = bf16_rne(bias[col]);  // bias.astype(bf16).astype(f32)
#pragma unroll
    for (int m = 0; m < 4; ++m) {
      const int r0 = rbase + m * 16 + hi * 4;
#pragma unroll
      for (int r = 0; r < 4; ++r) {
        const int row = r0 + r;
        // reference order: (acc * act_scale) * w_scale + bias_bf16, then bf16 RNE
        float v = (acc[m][n][r] * asc[row]) * wv + bb;
        out[(size_t)row * N + col] = bf16_rne(v);
      }
    }
  }
}

extern "C" void kernel_launch(void* const* d_in, const int* in_sizes, int n_in,
                              void* d_out, int out_size, void* d_ws, size_t ws_size,
                              hipStream_t stream) {
  const float* x = (const float*)d_in[0];     // [B,S,K] f32
  const float* w = (const float*)d_in[1];     // [N,K] f32
  const float* bias = (const float*)d_in[2];  // [N] f32
  float* out = (float*)d_out;                 // [M,N] f32 (bf16-rounded values)

  const int N = in_sizes[2];             // 4096 (D_OUT)
  const int K = in_sizes[1] / N;         // 4096 (D_IN)
  const int M = in_sizes[0] / K;         // 8192 tokens

  uint8_t* x8 = (uint8_t*)d_ws;                    // M*K bytes
  uint8_t* w8 = x8 + (size_t)M * K;                // N*K bytes
  float* asc = (float*)(w8 + (size_t)N * K);       // M floats
  float* wsc = asc + M;                            // N floats
  (void)ws_size; (void)n_in; (void)out_size;

  quant_rows_kernel<false><<<M, 256, 0, stream>>>(x, x8, asc, K);
  quant_rows_kernel<true><<<N, 256, 0, stream>>>(w, w8, wsc, K);
  gemm_fp8_kernel<<<(M / BM) * (N / BN), 256, 0, stream>>>(x8, w8, asc, wsc, bias, out, M, N, K);
}